// Round 7
// baseline (879.207 us; speedup 1.0000x reference)
//
#include <hip/hip_runtime.h>
#include <hip/hip_bf16.h>
#include <stdint.h>

typedef __attribute__((ext_vector_type(8))) short short8_t;    // 8 x bf16 (4 VGPRs)
typedef __attribute__((ext_vector_type(4))) float f32x4;       // nt vec
typedef __attribute__((ext_vector_type(16))) float f32x16;     // 32x32 MFMA accum

__device__ __forceinline__ unsigned short f2bf(float f) {
  union { float f; unsigned int u; } a;
  a.f = f;
  unsigned int u = a.u;
  u += 0x7fffu + ((u >> 16) & 1u);   // round-to-nearest-even
  return (unsigned short)(u >> 16);
}

__device__ __forceinline__ void gload_lds16(const void* g, void* l) {
  __builtin_amdgcn_global_load_lds(
      (const __attribute__((address_space(1))) void*)g,
      (__attribute__((address_space(3))) void*)l, 16, 0, 0);
}

// ---------------- LayerNorm: fp32 -> bf16 normed rows ----------------
constexpr int D_IN = 4096;

__global__ __launch_bounds__(256) void ln_bf16_kernel(
    const float* __restrict__ x, const float* __restrict__ lnw,
    const float* __restrict__ lnb, unsigned short* __restrict__ out) {
  const int row = blockIdx.x;
  const int tid = threadIdx.x;
  const float* xr = x + (size_t)row * D_IN;

  f32x4 v[4];
  float sum = 0.f, sq = 0.f;
#pragma unroll
  for (int i = 0; i < 4; ++i) {
    v[i] = __builtin_nontemporal_load(
        reinterpret_cast<const f32x4*>(xr + i * 1024 + tid * 4));
    sum += v[i][0] + v[i][1] + v[i][2] + v[i][3];
    sq += v[i][0]*v[i][0] + v[i][1]*v[i][1] + v[i][2]*v[i][2] + v[i][3]*v[i][3];
  }
#pragma unroll
  for (int off = 32; off > 0; off >>= 1) {
    sum += __shfl_down(sum, off, 64);
    sq  += __shfl_down(sq, off, 64);
  }
  __shared__ float s_sum[4], s_sq[4];
  if ((tid & 63) == 0) { s_sum[tid >> 6] = sum; s_sq[tid >> 6] = sq; }
  __syncthreads();
  const float fs = s_sum[0] + s_sum[1] + s_sum[2] + s_sum[3];
  const float fq = s_sq[0] + s_sq[1] + s_sq[2] + s_sq[3];
  const float mean = fs * (1.f / D_IN);
  const float var = fq * (1.f / D_IN) - mean * mean;
  const float rstd = rsqrtf(var + 1e-5f);

  unsigned short* orow = out + (size_t)row * D_IN;
#pragma unroll
  for (int i = 0; i < 4; ++i) {
    const int col = i * 1024 + tid * 4;
    const f32x4 w = *reinterpret_cast<const f32x4*>(lnw + col);
    const f32x4 b = *reinterpret_cast<const f32x4*>(lnb + col);
    ushort4 o;
    o.x = f2bf((v[i][0] - mean) * rstd * w[0] + b[0]);
    o.y = f2bf((v[i][1] - mean) * rstd * w[1] + b[1]);
    o.z = f2bf((v[i][2] - mean) * rstd * w[2] + b[2]);
    o.w = f2bf((v[i][3] - mean) * rstd * w[3] + b[3]);
    *reinterpret_cast<ushort4*>(orow + col) = o;
  }
}

// ---------------- Weight cast fp32 -> bf16 ----------------
__global__ __launch_bounds__(256) void f32_to_bf16_kernel(
    const float* __restrict__ in, unsigned short* __restrict__ out) {
  const size_t i = ((size_t)blockIdx.x * 256 + threadIdx.x) * 8;
  const f32x4 a = __builtin_nontemporal_load(reinterpret_cast<const f32x4*>(in + i));
  const f32x4 b = __builtin_nontemporal_load(reinterpret_cast<const f32x4*>(in + i + 4));
  ushort4 lo, hi;
  lo.x = f2bf(a[0]); lo.y = f2bf(a[1]); lo.z = f2bf(a[2]); lo.w = f2bf(a[3]);
  hi.x = f2bf(b[0]); hi.y = f2bf(b[1]); hi.z = f2bf(b[2]); hi.w = f2bf(b[3]);
  *reinterpret_cast<ushort4*>(out + i) = lo;
  *reinterpret_cast<ushort4*>(out + i + 4) = hi;
}

// ---------------- 256x256 8-phase bf16 GEMM (32x32x16 MFMA) ------
// C = A(MxK) * B(NxK)^T + bias.  8 waves (2M x 4N), BK=64, 2 K-tiles/iter.
// LDS: A slot0/1 @ 0/32K, B slot0/1 @ 64K/96K; swizzle byte ^= ((row&7)<<4)
// (verified 0 conflicts).  Read addr = laneBase[kf] + imm(S,mt) only.
// Per wave: 4x2 tiles of 32x32; per phase: 2 tiles x 4 k-frags = 8 MFMA.
// A-frag: lane->row=l&31, k=(l>>5)*8; C/D: col=l&31, row=(reg&3)+8(reg>>2)+4(l>>5).
// lgkm drain moved POST-MFMA (counted waits inside cluster, full drain at
// phase end preserves the stage-write barrier invariant).

#define RDF(P, IMM) (*reinterpret_cast<const short8_t*>((P) + (IMM)))

#define READ_A(S, MH)                                                 \
  _Pragma("unroll") for (int i_ = 0; i_ < 2; ++i_) {                  \
    _Pragma("unroll") for (int kf_ = 0; kf_ < 4; ++kf_)               \
      af[i_][kf_] = RDF(aA[kf_], (S)*32768 + ((MH)*2 + i_)*4096);     \
  }
#define READ_B0(S)                                                    \
  _Pragma("unroll") for (int kf_ = 0; kf_ < 4; ++kf_)                 \
      bf0[kf_] = RDF(bA[kf_], (S)*32768);
#define READ_B1(S)                                                    \
  _Pragma("unroll") for (int kf_ = 0; kf_ < 4; ++kf_)                 \
      bf1[kf_] = RDF(bA[kf_], (S)*32768 + 4096);

#define MFMA_Q(MH, NH, BF)                                            \
  _Pragma("unroll") for (int kf_ = 0; kf_ < 4; ++kf_) {               \
    _Pragma("unroll") for (int i_ = 0; i_ < 2; ++i_)                  \
      acc[(MH)*2 + i_][NH] = __builtin_amdgcn_mfma_f32_32x32x16_bf16( \
          af[i_][kf_], BF[kf_], acc[(MH)*2 + i_][NH], 0, 0, 0);       \
  }

#define STAGE_A(S, U, KT) \
  gload_lds16(aSrc + (size_t)((U)*64) * K + (size_t)(KT)*64, ldsAw + (S)*32768 + (U)*8192)
#define STAGE_B(S, U, KT) \
  gload_lds16(bSrc + (size_t)((U)*64) * K + (size_t)(KT)*64, ldsBw + (S)*32768 + (U)*8192)

#define PH_MID                                         \
  __builtin_amdgcn_s_barrier();                        \
  __builtin_amdgcn_s_setprio(1)
#define PH_END                                         \
  __builtin_amdgcn_s_setprio(0);                       \
  asm volatile("s_waitcnt lgkmcnt(0)" ::: "memory");   \
  __builtin_amdgcn_s_barrier();                        \
  asm volatile("" ::: "memory")
#define PH_END_V(N)                                    \
  __builtin_amdgcn_s_setprio(0);                       \
  asm volatile("s_waitcnt lgkmcnt(0)\n\ts_waitcnt vmcnt(" #N ")" ::: "memory");\
  __builtin_amdgcn_s_barrier();                        \
  asm volatile("" ::: "memory")

__global__ __launch_bounds__(512, 2) void gemm_8phase(
    const unsigned short* __restrict__ A,   // M x K bf16
    const unsigned short* __restrict__ B,   // N x K bf16
    const float* __restrict__ bias,         // N fp32
    float* __restrict__ C,                  // M x N fp32
    int M, int N, int K, int NYB, int BXP) {
  extern __shared__ char smem[];
  const int tid = threadIdx.x;
  const int lane = tid & 63;
  const int wid = tid >> 6;
  const int wr = wid >> 2, wc = wid & 3;
  const int l31 = lane & 31;
  const int kh = lane >> 5;
  const int l7 = lane & 7;
  const int wr128 = wr * 128;
  const int wc64 = wc * 64;

  // XCD mapping: XCD x owns bx in [x*BXP, (x+1)*BXP)
  const int id = blockIdx.x;
  const int xcd = id & 7;
  const int slot = id >> 3;
  const int by = slot % NYB;
  const int bx = xcd * BXP + slot / NYB;
  const int m0 = by * 256, n0 = bx * 256;

  // inverse-swizzled global source for linear global_load_lds dest
  const int s_log = (tid * 16) ^ (((tid >> 3) & 7) << 4);
  const int rsw = s_log >> 7;
  const int csw = (s_log & 127) >> 1;
  const unsigned short* aSrc = A + (size_t)(m0 + rsw) * K + csw;
  const unsigned short* bSrc = B + (size_t)(n0 + rsw) * K + csw;

  char* const ldsAw = smem + wid * 1024;           // wave-uniform stage bases
  char* const ldsBw = smem + 65536 + wid * 1024;

  // per-lane fragment read bases: addr = base[kf] + (S*32768 + tile*4096)
  const char* aA[4];
  const char* bA[4];
#pragma unroll
  for (int kf = 0; kf < 4; ++kf) {
    const int sl = ((((kf << 1) | kh) ^ l7) << 4);
    aA[kf] = smem + (wr128 + l31) * 128 + sl;
    bA[kf] = smem + 65536 + (wc64 + l31) * 128 + sl;
  }

  f32x16 acc[4][2] = {};      // [mt][nt]
  short8_t af[2][4], bf0[4], bf1[4];

  // ---- prologue: ktile0 -> slot0 (8 units), ktile1 -> slot1 (6 units) ----
  STAGE_A(0,0,0); STAGE_A(0,1,0); STAGE_A(0,2,0); STAGE_A(0,3,0);
  STAGE_B(0,0,0); STAGE_B(0,1,0); STAGE_B(0,2,0); STAGE_B(0,3,0);
  STAGE_A(1,0,1); STAGE_A(1,1,1); STAGE_A(1,2,1); STAGE_A(1,3,1);
  STAGE_B(1,0,1); STAGE_B(1,1,1);
  asm volatile("s_waitcnt vmcnt(6)" ::: "memory");   // slot0 landed
  __builtin_amdgcn_s_barrier();
  asm volatile("" ::: "memory");

  const int NT = K >> 7;   // 2 K-tiles (2*64) per iteration
  for (int t = 0; t < NT - 1; ++t) {
    const int k1 = 2*t + 1, k2 = 2*t + 2, k3 = 2*t + 3;
    // P1: 12 ds_reads; stage slot1 B-tail (lands by P4 vmcnt)
    READ_A(0, 0) READ_B0(0)
    STAGE_B(1,2,k1); STAGE_B(1,3,k1);
    PH_MID; MFMA_Q(0,0,bf0) PH_END;
    // P2: stage slot0 A units 0,2 (freed by P1 reads)
    READ_B1(0)
    STAGE_A(0,0,k2); STAGE_A(0,2,k2);
    PH_MID; MFMA_Q(0,1,bf1) PH_END;
    // P3: stage slot0 B units 0,1
    READ_A(0, 1)
    STAGE_B(0,0,k2); STAGE_B(0,1,k2);
    PH_MID; MFMA_Q(1,0,bf0) PH_END;
    // P4: stage slot0 A units 1,3; counted vmcnt -> slot1 landed
    STAGE_A(0,1,k2); STAGE_A(0,3,k2);
    PH_MID; MFMA_Q(1,1,bf1) PH_END_V(6);
    // P5: 12 ds_reads on slot1; stage slot0 B units 2,3
    READ_A(1, 0) READ_B0(1)
    STAGE_B(0,2,k2); STAGE_B(0,3,k2);
    PH_MID; MFMA_Q(0,0,bf0) PH_END;
    // P6: stage slot1 A units 0,2
    READ_B1(1)
    STAGE_A(1,0,k3); STAGE_A(1,2,k3);
    PH_MID; MFMA_Q(0,1,bf1) PH_END;
    // P7: stage slot1 B units 0,1
    READ_A(1, 1)
    STAGE_B(1,0,k3); STAGE_B(1,1,k3);
    PH_MID; MFMA_Q(1,0,bf0) PH_END;
    // P8: stage slot1 A units 1,3; counted vmcnt -> slot0 landed
    STAGE_A(1,1,k3); STAGE_A(1,3,k3);
    PH_MID; MFMA_Q(1,1,bf1) PH_END_V(6);
  }
  // ---- final iteration: only the slot1 B-tail stage remains ----
  {
    const int k1 = 2*NT - 1;
    READ_A(0, 0) READ_B0(0)
    STAGE_B(1,2,k1); STAGE_B(1,3,k1);
    PH_MID; MFMA_Q(0,0,bf0) PH_END;
    READ_B1(0)
    PH_MID; MFMA_Q(0,1,bf1) PH_END;
    READ_A(0, 1)
    PH_MID; MFMA_Q(1,0,bf0) PH_END;
    PH_MID; MFMA_Q(1,1,bf1) PH_END_V(0);
    READ_A(1, 0) READ_B0(1)
    PH_MID; MFMA_Q(0,0,bf0) PH_END;
    READ_B1(1)
    PH_MID; MFMA_Q(0,1,bf1) PH_END;
    READ_A(1, 1)
    PH_MID; MFMA_Q(1,0,bf0) PH_END;
    PH_MID; MFMA_Q(1,1,bf1)
    __builtin_amdgcn_s_setprio(0);
  }

  // ---- epilogue: LDS-transpose -> fully-contiguous 1KB nt stores ----
  __syncthreads();   // drains all counters; K-loop LDS free to reuse
  float* const buf0 = (float*)smem;
  float* const buf1 = (float*)smem + 64 * 260;
  float bv[2];
#pragma unroll
  for (int nt = 0; nt < 2; ++nt) bv[nt] = bias[n0 + wc64 + nt * 32 + l31];

#pragma unroll
  for (int half = 0; half < 2; ++half) {
    float* const wbuf = (wr == 0) ? buf0 : buf1;
#pragma unroll
    for (int im = 0; im < 2; ++im) {          // mt = half*2 + im
#pragma unroll
      for (int reg = 0; reg < 16; ++reg) {
        const int lr = im * 32 + (reg & 3) + 8 * (reg >> 2) + 4 * kh;  // 0..63
#pragma unroll
        for (int nt = 0; nt < 2; ++nt)
          wbuf[lr * 260 + wc64 + nt * 32 + l31] = acc[half*2 + im][nt][reg] + bv[nt];
      }
    }
    __syncthreads();
#pragma unroll
    for (int i = 0; i < 16; ++i) {
      const int idx = wid * 16 + i;   // 0..127, wave-uniform buffer choice
      const float* src = (idx < 64 ? buf0 + idx * 260 : buf1 + (idx - 64) * 260) + lane * 4;
      const int grow = m0 + (idx < 64 ? half * 64 + idx : 128 + half * 64 + (idx - 64));
      const f32x4 vv = *reinterpret_cast<const f32x4*>(src);
      __builtin_nontemporal_store(
          vv, reinterpret_cast<f32x4*>(C + (size_t)grow * N + n0) + lane);
    }
    __syncthreads();
  }
}

extern "C" void kernel_launch(void* const* d_in, const int* in_sizes, int n_in,
                              void* d_out, int out_size, void* d_ws, size_t ws_size,
                              hipStream_t stream) {
  const float* x    = (const float*)d_in[0];
  const float* w    = (const float*)d_in[1];
  const float* bias = (const float*)d_in[2];
  const float* lnw  = (const float*)d_in[3];
  const float* lnb  = (const float*)d_in[4];
  float* out = (float*)d_out;

  const int DIN  = 4096;
  const int M    = in_sizes[0] / DIN;      // 8192
  const int DOUT = in_sizes[2];            // 12288

  unsigned short* normA = (unsigned short*)d_ws;                 // M x DIN bf16
  unsigned short* wB    = normA + (size_t)M * DIN;               // DOUT x DIN bf16

  ln_bf16_kernel<<<M, 256, 0, stream>>>(x, lnw, lnb, normA);
  f32_to_bf16_kernel<<<((size_t)DOUT * DIN) / (256 * 8), 256, 0, stream>>>(w, wB);

  const int nwg = (M / 256) * (DOUT / 256);   // 1536
  const int smem_bytes = 2 * 64 * 260 * 4 > 131072 ? 2 * 64 * 260 * 4 : 131072; // 133120
  (void)hipFuncSetAttribute((const void*)gemm_8phase,
                            hipFuncAttributeMaxDynamicSharedMemorySize, 163840);
  gemm_8phase<<<nwg, 512, smem_bytes, stream>>>(normA, wB, bias, out,
                                                M, DOUT, DIN, M / 256, (DOUT / 256) / 8);
}

// Round 8
// 876.911 us; speedup vs baseline: 1.0026x; 1.0026x over previous
//
#include <hip/hip_runtime.h>
#include <hip/hip_bf16.h>
#include <stdint.h>

typedef __attribute__((ext_vector_type(8))) short short8_t;    // 8 x bf16 (4 VGPRs)
typedef __attribute__((ext_vector_type(4))) float f32x4;       // nt vec
typedef __attribute__((ext_vector_type(16))) float f32x16;     // 32x32 MFMA accum

__device__ __forceinline__ unsigned short f2bf(float f) {
  union { float f; unsigned int u; } a;
  a.f = f;
  unsigned int u = a.u;
  u += 0x7fffu + ((u >> 16) & 1u);   // round-to-nearest-even
  return (unsigned short)(u >> 16);
}

__device__ __forceinline__ void gload_lds16(const void* g, void* l) {
  __builtin_amdgcn_global_load_lds(
      (const __attribute__((address_space(1))) void*)g,
      (__attribute__((address_space(3))) void*)l, 16, 0, 0);
}

// ---------------- LayerNorm: fp32 -> bf16 normed rows ----------------
constexpr int D_IN = 4096;

__global__ __launch_bounds__(256) void ln_bf16_kernel(
    const float* __restrict__ x, const float* __restrict__ lnw,
    const float* __restrict__ lnb, unsigned short* __restrict__ out) {
  const int row = blockIdx.x;
  const int tid = threadIdx.x;
  const float* xr = x + (size_t)row * D_IN;

  f32x4 v[4];
  float sum = 0.f, sq = 0.f;
#pragma unroll
  for (int i = 0; i < 4; ++i) {
    v[i] = __builtin_nontemporal_load(
        reinterpret_cast<const f32x4*>(xr + i * 1024 + tid * 4));
    sum += v[i][0] + v[i][1] + v[i][2] + v[i][3];
    sq += v[i][0]*v[i][0] + v[i][1]*v[i][1] + v[i][2]*v[i][2] + v[i][3]*v[i][3];
  }
#pragma unroll
  for (int off = 32; off > 0; off >>= 1) {
    sum += __shfl_down(sum, off, 64);
    sq  += __shfl_down(sq, off, 64);
  }
  __shared__ float s_sum[4], s_sq[4];
  if ((tid & 63) == 0) { s_sum[tid >> 6] = sum; s_sq[tid >> 6] = sq; }
  __syncthreads();
  const float fs = s_sum[0] + s_sum[1] + s_sum[2] + s_sum[3];
  const float fq = s_sq[0] + s_sq[1] + s_sq[2] + s_sq[3];
  const float mean = fs * (1.f / D_IN);
  const float var = fq * (1.f / D_IN) - mean * mean;
  const float rstd = rsqrtf(var + 1e-5f);

  unsigned short* orow = out + (size_t)row * D_IN;
#pragma unroll
  for (int i = 0; i < 4; ++i) {
    const int col = i * 1024 + tid * 4;
    const f32x4 w = *reinterpret_cast<const f32x4*>(lnw + col);
    const f32x4 b = *reinterpret_cast<const f32x4*>(lnb + col);
    ushort4 o;
    o.x = f2bf((v[i][0] - mean) * rstd * w[0] + b[0]);
    o.y = f2bf((v[i][1] - mean) * rstd * w[1] + b[1]);
    o.z = f2bf((v[i][2] - mean) * rstd * w[2] + b[2]);
    o.w = f2bf((v[i][3] - mean) * rstd * w[3] + b[3]);
    *reinterpret_cast<ushort4*>(orow + col) = o;
  }
}

// ---------------- Weight cast fp32 -> bf16 ----------------
__global__ __launch_bounds__(256) void f32_to_bf16_kernel(
    const float* __restrict__ in, unsigned short* __restrict__ out) {
  const size_t i = ((size_t)blockIdx.x * 256 + threadIdx.x) * 8;
  const f32x4 a = __builtin_nontemporal_load(reinterpret_cast<const f32x4*>(in + i));
  const f32x4 b = __builtin_nontemporal_load(reinterpret_cast<const f32x4*>(in + i + 4));
  ushort4 lo, hi;
  lo.x = f2bf(a[0]); lo.y = f2bf(a[1]); lo.z = f2bf(a[2]); lo.w = f2bf(a[3]);
  hi.x = f2bf(b[0]); hi.y = f2bf(b[1]); hi.z = f2bf(b[2]); hi.w = f2bf(b[3]);
  *reinterpret_cast<ushort4*>(out + i) = lo;
  *reinterpret_cast<ushort4*>(out + i + 4) = hi;
}

// ---------------- 256x256 8-phase bf16 GEMM (32x32x16 MFMA) ------
// C = A(MxK) * B(NxK)^T + bias.  8 waves (2M x 4N), BK=64, 2 K-tiles/iter.
// LDS: A slot0/1 @ 0/32K, B slot0/1 @ 64K/96K.
// Swizzle (5-bit): byte ^= f(row)<<4, f(row) = (row&7) ^ (((row>>3)&3)<<1).
//   Read slot = (kf*2+kh) ^ (l&7) ^ (((l>>3)&3)<<1): all 8 slots distinct
//   within every stride-8 lane class AND uniform 8/slot wave-wide
//   (r2/r6/r7-calibrated bank rule) -> conflict-free b128 reads.
// Read addr = laneBase[kf] + imm (tile steps are 32-row multiples: slot-safe).
// Stage: linear LDS dest (global_load_lds), inverse-swizzled global source.
// lgkm drain POST-MFMA (counted waits inside cluster, full drain at phase end
// preserves the stage-write barrier invariant).

#define RDF(P, IMM) (*reinterpret_cast<const short8_t*>((P) + (IMM)))

#define READ_A(S, MH)                                                 \
  _Pragma("unroll") for (int i_ = 0; i_ < 2; ++i_) {                  \
    _Pragma("unroll") for (int kf_ = 0; kf_ < 4; ++kf_)               \
      af[i_][kf_] = RDF(aA[kf_], (S)*32768 + ((MH)*2 + i_)*4096);     \
  }
#define READ_B0(S)                                                    \
  _Pragma("unroll") for (int kf_ = 0; kf_ < 4; ++kf_)                 \
      bf0[kf_] = RDF(bA[kf_], (S)*32768);
#define READ_B1(S)                                                    \
  _Pragma("unroll") for (int kf_ = 0; kf_ < 4; ++kf_)                 \
      bf1[kf_] = RDF(bA[kf_], (S)*32768 + 4096);

#define MFMA_Q(MH, NH, BF)                                            \
  _Pragma("unroll") for (int kf_ = 0; kf_ < 4; ++kf_) {               \
    _Pragma("unroll") for (int i_ = 0; i_ < 2; ++i_)                  \
      acc[(MH)*2 + i_][NH] = __builtin_amdgcn_mfma_f32_32x32x16_bf16( \
          af[i_][kf_], BF[kf_], acc[(MH)*2 + i_][NH], 0, 0, 0);       \
  }

#define STAGE_A(S, U, KT) \
  gload_lds16(aSrc + (size_t)((U)*64) * K + (size_t)(KT)*64, ldsAw + (S)*32768 + (U)*8192)
#define STAGE_B(S, U, KT) \
  gload_lds16(bSrc + (size_t)((U)*64) * K + (size_t)(KT)*64, ldsBw + (S)*32768 + (U)*8192)

#define PH_MID                                         \
  __builtin_amdgcn_s_barrier();                        \
  __builtin_amdgcn_s_setprio(1)
#define PH_END                                         \
  __builtin_amdgcn_s_setprio(0);                       \
  asm volatile("s_waitcnt lgkmcnt(0)" ::: "memory");   \
  __builtin_amdgcn_s_barrier();                        \
  asm volatile("" ::: "memory")
#define PH_END_V(N)                                    \
  __builtin_amdgcn_s_setprio(0);                       \
  asm volatile("s_waitcnt lgkmcnt(0)\n\ts_waitcnt vmcnt(" #N ")" ::: "memory");\
  __builtin_amdgcn_s_barrier();                        \
  asm volatile("" ::: "memory")

__global__ __launch_bounds__(512, 2) void gemm_8phase(
    const unsigned short* __restrict__ A,   // M x K bf16
    const unsigned short* __restrict__ B,   // N x K bf16
    const float* __restrict__ bias,         // N fp32
    float* __restrict__ C,                  // M x N fp32
    int M, int N, int K, int NYB, int BXP) {
  extern __shared__ char smem[];
  const int tid = threadIdx.x;
  const int lane = tid & 63;
  const int wid = tid >> 6;
  const int wr = wid >> 2, wc = wid & 3;
  const int l31 = lane & 31;
  const int kh = lane >> 5;
  const int l7 = lane & 7;
  const int wr128 = wr * 128;
  const int wc64 = wc * 64;

  // XCD mapping: XCD x owns bx in [x*BXP, (x+1)*BXP)
  const int id = blockIdx.x;
  const int xcd = id & 7;
  const int slot = id >> 3;
  const int by = slot % NYB;
  const int bx = xcd * BXP + slot / NYB;
  const int m0 = by * 256, n0 = bx * 256;

  // inverse-swizzled global source for linear global_load_lds dest
  // staged row = tid>>3; f(row) = (row&7) ^ (((row>>3)&3)<<1)
  const int r_st = tid >> 3;
  const int fsw = (r_st & 7) ^ (((r_st >> 3) & 3) << 1);
  const int s_log = (tid * 16) ^ (fsw << 4);
  const int rsw = s_log >> 7;
  const int csw = (s_log & 127) >> 1;
  const unsigned short* aSrc = A + (size_t)(m0 + rsw) * K + csw;
  const unsigned short* bSrc = B + (size_t)(n0 + rsw) * K + csw;

  char* const ldsAw = smem + wid * 1024;           // wave-uniform stage bases
  char* const ldsBw = smem + 65536 + wid * 1024;

  // per-lane fragment read bases: addr = base[kf] + (S*32768 + tile*4096)
  const int fswr = l7 ^ (((l31 >> 3) & 3) << 1);   // f(row) for row = l31
  const char* aA[4];
  const char* bA[4];
#pragma unroll
  for (int kf = 0; kf < 4; ++kf) {
    const int sl = ((((kf << 1) | kh) ^ fswr) << 4);
    aA[kf] = smem + (wr128 + l31) * 128 + sl;
    bA[kf] = smem + 65536 + (wc64 + l31) * 128 + sl;
  }

  f32x16 acc[4][2] = {};      // [mt][nt]
  short8_t af[2][4], bf0[4], bf1[4];

  // ---- prologue: ktile0 -> slot0 (8 units), ktile1 -> slot1 (6 units) ----
  STAGE_A(0,0,0); STAGE_A(0,1,0); STAGE_A(0,2,0); STAGE_A(0,3,0);
  STAGE_B(0,0,0); STAGE_B(0,1,0); STAGE_B(0,2,0); STAGE_B(0,3,0);
  STAGE_A(1,0,1); STAGE_A(1,1,1); STAGE_A(1,2,1); STAGE_A(1,3,1);
  STAGE_B(1,0,1); STAGE_B(1,1,1);
  asm volatile("s_waitcnt vmcnt(6)" ::: "memory");   // slot0 landed
  __builtin_amdgcn_s_barrier();
  asm volatile("" ::: "memory");

  const int NT = K >> 7;   // 2 K-tiles (2*64) per iteration
  for (int t = 0; t < NT - 1; ++t) {
    const int k1 = 2*t + 1, k2 = 2*t + 2, k3 = 2*t + 3;
    // P1: 12 ds_reads; stage slot1 B-tail (lands by P4 vmcnt)
    READ_A(0, 0) READ_B0(0)
    STAGE_B(1,2,k1); STAGE_B(1,3,k1);
    PH_MID; MFMA_Q(0,0,bf0) PH_END;
    // P2: stage slot0 A units 0,2 (freed by P1 reads)
    READ_B1(0)
    STAGE_A(0,0,k2); STAGE_A(0,2,k2);
    PH_MID; MFMA_Q(0,1,bf1) PH_END;
    // P3: stage slot0 B units 0,1
    READ_A(0, 1)
    STAGE_B(0,0,k2); STAGE_B(0,1,k2);
    PH_MID; MFMA_Q(1,0,bf0) PH_END;
    // P4: stage slot0 A units 1,3; counted vmcnt -> slot1 landed
    STAGE_A(0,1,k2); STAGE_A(0,3,k2);
    PH_MID; MFMA_Q(1,1,bf1) PH_END_V(6);
    // P5: 12 ds_reads on slot1; stage slot0 B units 2,3
    READ_A(1, 0) READ_B0(1)
    STAGE_B(0,2,k2); STAGE_B(0,3,k2);
    PH_MID; MFMA_Q(0,0,bf0) PH_END;
    // P6: stage slot1 A units 0,2
    READ_B1(1)
    STAGE_A(1,0,k3); STAGE_A(1,2,k3);
    PH_MID; MFMA_Q(0,1,bf1) PH_END;
    // P7: stage slot1 B units 0,1
    READ_A(1, 1)
    STAGE_B(1,0,k3); STAGE_B(1,1,k3);
    PH_MID; MFMA_Q(1,0,bf0) PH_END;
    // P8: stage slot1 A units 1,3; counted vmcnt -> slot0 landed
    STAGE_A(1,1,k3); STAGE_A(1,3,k3);
    PH_MID; MFMA_Q(1,1,bf1) PH_END_V(6);
  }
  // ---- final iteration: only the slot1 B-tail stage remains ----
  {
    const int k1 = 2*NT - 1;
    READ_A(0, 0) READ_B0(0)
    STAGE_B(1,2,k1); STAGE_B(1,3,k1);
    PH_MID; MFMA_Q(0,0,bf0) PH_END;
    READ_B1(0)
    PH_MID; MFMA_Q(0,1,bf1) PH_END;
    READ_A(0, 1)
    PH_MID; MFMA_Q(1,0,bf0) PH_END;
    PH_MID; MFMA_Q(1,1,bf1) PH_END_V(0);
    READ_A(1, 0) READ_B0(1)
    PH_MID; MFMA_Q(0,0,bf0) PH_END;
    READ_B1(1)
    PH_MID; MFMA_Q(0,1,bf1) PH_END;
    READ_A(1, 1)
    PH_MID; MFMA_Q(1,0,bf0) PH_END;
    PH_MID; MFMA_Q(1,1,bf1)
    __builtin_amdgcn_s_setprio(0);
  }

  // ---- epilogue: LDS-transpose -> fully-contiguous 1KB nt stores ----
  __syncthreads();   // drains all counters; K-loop LDS free to reuse
  float* const buf0 = (float*)smem;
  float* const buf1 = (float*)smem + 64 * 260;
  float bv[2];
#pragma unroll
  for (int nt = 0; nt < 2; ++nt) bv[nt] = bias[n0 + wc64 + nt * 32 + l31];

#pragma unroll
  for (int half = 0; half < 2; ++half) {
    float* const wbuf = (wr == 0) ? buf0 : buf1;
#pragma unroll
    for (int im = 0; im < 2; ++im) {          // mt = half*2 + im
#pragma unroll
      for (int reg = 0; reg < 16; ++reg) {
        const int lr = im * 32 + (reg & 3) + 8 * (reg >> 2) + 4 * kh;  // 0..63
#pragma unroll
        for (int nt = 0; nt < 2; ++nt)
          wbuf[lr * 260 + wc64 + nt * 32 + l31] = acc[half*2 + im][nt][reg] + bv[nt];
      }
    }
    __syncthreads();
#pragma unroll
    for (int i = 0; i < 16; ++i) {
      const int idx = wid * 16 + i;   // 0..127, wave-uniform buffer choice
      const float* src = (idx < 64 ? buf0 + idx * 260 : buf1 + (idx - 64) * 260) + lane * 4;
      const int grow = m0 + (idx < 64 ? half * 64 + idx : 128 + half * 64 + (idx - 64));
      const f32x4 vv = *reinterpret_cast<const f32x4*>(src);
      __builtin_nontemporal_store(
          vv, reinterpret_cast<f32x4*>(C + (size_t)grow * N + n0) + lane);
    }
    __syncthreads();
  }
}

extern "C" void kernel_launch(void* const* d_in, const int* in_sizes, int n_in,
                              void* d_out, int out_size, void* d_ws, size_t ws_size,
                              hipStream_t stream) {
  const float* x    = (const float*)d_in[0];
  const float* w    = (const float*)d_in[1];
  const float* bias = (const float*)d_in[2];
  const float* lnw  = (const float*)d_in[3];
  const float* lnb  = (const float*)d_in[4];
  float* out = (float*)d_out;

  const int DIN  = 4096;
  const int M    = in_sizes[0] / DIN;      // 8192
  const int DOUT = in_sizes[2];            // 12288

  unsigned short* normA = (unsigned short*)d_ws;                 // M x DIN bf16
  unsigned short* wB    = normA + (size_t)M * DIN;               // DOUT x DIN bf16

  ln_bf16_kernel<<<M, 256, 0, stream>>>(x, lnw, lnb, normA);
  f32_to_bf16_kernel<<<((size_t)DOUT * DIN) / (256 * 8), 256, 0, stream>>>(w, wB);

  const int nwg = (M / 256) * (DOUT / 256);   // 1536
  const int smem_bytes = 2 * 64 * 260 * 4 > 131072 ? 2 * 64 * 260 * 4 : 131072; // 133120
  (void)hipFuncSetAttribute((const void*)gemm_8phase,
                            hipFuncAttributeMaxDynamicSharedMemorySize, 163840);
  gemm_8phase<<<nwg, 512, smem_bytes, stream>>>(normA, wB, bias, out,
                                                M, DOUT, DIN, M / 256, (DOUT / 256) / 8);
}

// Round 9
// 769.706 us; speedup vs baseline: 1.1423x; 1.1393x over previous
//
#include <hip/hip_runtime.h>
#include <hip/hip_bf16.h>
#include <stdint.h>

typedef __attribute__((ext_vector_type(8))) short short8_t;   // 8 x bf16 (4 VGPRs)
typedef __attribute__((ext_vector_type(4))) float f32x4;      // MFMA accum / nt vec

__device__ __forceinline__ unsigned short f2bf(float f) {
  union { float f; unsigned int u; } a;
  a.f = f;
  unsigned int u = a.u;
  u += 0x7fffu + ((u >> 16) & 1u);   // round-to-nearest-even
  return (unsigned short)(u >> 16);
}

__device__ __forceinline__ void gload_lds16(const void* g, void* l) {
  __builtin_amdgcn_global_load_lds(
      (const __attribute__((address_space(1))) void*)g,
      (__attribute__((address_space(3))) void*)l, 16, 0, 0);
}

// ---------------- LayerNorm: fp32 -> bf16 normed rows ----------------
constexpr int D_IN = 4096;

__global__ __launch_bounds__(256) void ln_bf16_kernel(
    const float* __restrict__ x, const float* __restrict__ lnw,
    const float* __restrict__ lnb, unsigned short* __restrict__ out) {
  const int row = blockIdx.x;
  const int tid = threadIdx.x;
  const float* xr = x + (size_t)row * D_IN;

  f32x4 v[4];
  float sum = 0.f, sq = 0.f;
#pragma unroll
  for (int i = 0; i < 4; ++i) {
    v[i] = __builtin_nontemporal_load(
        reinterpret_cast<const f32x4*>(xr + i * 1024 + tid * 4));
    sum += v[i][0] + v[i][1] + v[i][2] + v[i][3];
    sq += v[i][0]*v[i][0] + v[i][1]*v[i][1] + v[i][2]*v[i][2] + v[i][3]*v[i][3];
  }
#pragma unroll
  for (int off = 32; off > 0; off >>= 1) {
    sum += __shfl_down(sum, off, 64);
    sq  += __shfl_down(sq, off, 64);
  }
  __shared__ float s_sum[4], s_sq[4];
  if ((tid & 63) == 0) { s_sum[tid >> 6] = sum; s_sq[tid >> 6] = sq; }
  __syncthreads();
  const float fs = s_sum[0] + s_sum[1] + s_sum[2] + s_sum[3];
  const float fq = s_sq[0] + s_sq[1] + s_sq[2] + s_sq[3];
  const float mean = fs * (1.f / D_IN);
  const float var = fq * (1.f / D_IN) - mean * mean;
  const float rstd = rsqrtf(var + 1e-5f);

  unsigned short* orow = out + (size_t)row * D_IN;
#pragma unroll
  for (int i = 0; i < 4; ++i) {
    const int col = i * 1024 + tid * 4;
    const f32x4 w = *reinterpret_cast<const f32x4*>(lnw + col);
    const f32x4 b = *reinterpret_cast<const f32x4*>(lnb + col);
    ushort4 o;
    o.x = f2bf((v[i][0] - mean) * rstd * w[0] + b[0]);
    o.y = f2bf((v[i][1] - mean) * rstd * w[1] + b[1]);
    o.z = f2bf((v[i][2] - mean) * rstd * w[2] + b[2]);
    o.w = f2bf((v[i][3] - mean) * rstd * w[3] + b[3]);
    *reinterpret_cast<ushort4*>(orow + col) = o;
  }
}

// ---------------- Weight cast fp32 -> bf16 ----------------
__global__ __launch_bounds__(256) void f32_to_bf16_kernel(
    const float* __restrict__ in, unsigned short* __restrict__ out) {
  const size_t i = ((size_t)blockIdx.x * 256 + threadIdx.x) * 8;
  const f32x4 a = __builtin_nontemporal_load(reinterpret_cast<const f32x4*>(in + i));
  const f32x4 b = __builtin_nontemporal_load(reinterpret_cast<const f32x4*>(in + i + 4));
  ushort4 lo, hi;
  lo.x = f2bf(a[0]); lo.y = f2bf(a[1]); lo.z = f2bf(a[2]); lo.w = f2bf(a[3]);
  hi.x = f2bf(b[0]); hi.y = f2bf(b[1]); hi.z = f2bf(b[2]); hi.w = f2bf(b[3]);
  *reinterpret_cast<ushort4*>(out + i) = lo;
  *reinterpret_cast<ushort4*>(out + i + 4) = hi;
}

// ---------------- 256x256 8-phase bf16 GEMM (r6 base, post-MFMA lgkm drain) --
// C = A(MxK) * B(NxK)^T + bias.  8 waves (2M x 4N), BK=64, 2 K-tiles/iter.
// LDS: A slot0/1 @ 0/32K, B slot0/1 @ 64K/96K.  16x16x32 MFMA (r6-proven).
// Swizzle byte ^= ((row&7)<<4): VERIFIED 0 conflicts (r3/r5/r6).
// Read addr = laneBase[kk] + imm only (r6's fix: zero per-phase addr VALU).
// SINGLE CHANGE vs r6: lgkm drain moved POST-MFMA — compiler emits counted
// lgkm waits before each MFMA operand use, so read returns overlap the MFMA
// stream; full drain at phase END preserves the stage-write WAR invariant.
// Stage: linear LDS dest (global_load_lds), inverse-swizzled global source.
// Epilogue: LDS-transposed, 1KB-contiguous nontemporal stores.

#define RDA(S, KK, ROW) \
  (*reinterpret_cast<const short8_t*>(((KK) ? aB1 : aB0) + (S)*32768 + (ROW)*128))
#define RDB(S, KK, ROW) \
  (*reinterpret_cast<const short8_t*>(((KK) ? bB1 : bB0) + (S)*32768 + (ROW)*128))

#define READ_A(S, MH)                                          \
  _Pragma("unroll") for (int m_ = 0; m_ < 4; ++m_) {           \
    af[m_][0] = RDA(S, 0, (MH)*64 + m_*16);                    \
    af[m_][1] = RDA(S, 1, (MH)*64 + m_*16);                    \
  }

#define READ_B(S, NH)                                          \
  _Pragma("unroll") for (int n_ = 0; n_ < 2; ++n_) {           \
    bfr[(NH)*2+n_][0] = RDB(S, 0, ((NH)*2+n_)*16);             \
    bfr[(NH)*2+n_][1] = RDB(S, 1, ((NH)*2+n_)*16);             \
  }

#define MFMA_Q(MH, NH)                                                         \
  _Pragma("unroll") for (int kk_ = 0; kk_ < 2; ++kk_) {                        \
    _Pragma("unroll") for (int m_ = 0; m_ < 4; ++m_) {                         \
      _Pragma("unroll") for (int n_ = 0; n_ < 2; ++n_)                         \
        acc[(MH)*4+m_][(NH)*2+n_] = __builtin_amdgcn_mfma_f32_16x16x32_bf16(   \
            af[m_][kk_], bfr[(NH)*2+n_][kk_], acc[(MH)*4+m_][(NH)*2+n_], 0, 0, 0); \
    }                                                                          \
  }

#define STAGE_A(S, U, KT) \
  gload_lds16(aSrc + (size_t)((U)*64) * K + (size_t)(KT)*64, ldsAw + (S)*32768 + (U)*8192)
#define STAGE_B(S, U, KT) \
  gload_lds16(bSrc + (size_t)((U)*64) * K + (size_t)(KT)*64, ldsBw + (S)*32768 + (U)*8192)

#define PH_MID                                         \
  __builtin_amdgcn_s_barrier();                        \
  __builtin_amdgcn_s_setprio(1)
#define PH_END                                         \
  __builtin_amdgcn_s_setprio(0);                       \
  asm volatile("s_waitcnt lgkmcnt(0)" ::: "memory");   \
  __builtin_amdgcn_s_barrier();                        \
  asm volatile("" ::: "memory")
#define PH_END_V(N)                                    \
  __builtin_amdgcn_s_setprio(0);                       \
  asm volatile("s_waitcnt lgkmcnt(0)\n\ts_waitcnt vmcnt(" #N ")" ::: "memory");\
  __builtin_amdgcn_s_barrier();                        \
  asm volatile("" ::: "memory")

__global__ __launch_bounds__(512, 2) void gemm_8phase(
    const unsigned short* __restrict__ A,   // M x K bf16
    const unsigned short* __restrict__ B,   // N x K bf16
    const float* __restrict__ bias,         // N fp32
    float* __restrict__ C,                  // M x N fp32
    int M, int N, int K, int NYB, int BXP) {
  extern __shared__ char smem[];
  const int tid = threadIdx.x;
  const int lane = tid & 63;
  const int wid = tid >> 6;
  const int wr = wid >> 2, wc = wid & 3;
  const int fr = lane & 15;
  const int q16 = (lane >> 4) * 16;
  const int wr128 = wr * 128;
  const int wc64 = wc * 64;

  // XCD mapping: XCD x owns bx in [x*BXP, (x+1)*BXP)
  const int id = blockIdx.x;
  const int xcd = id & 7;
  const int slot = id >> 3;
  const int by = slot % NYB;
  const int bx = xcd * BXP + slot / NYB;
  const int m0 = by * 256, n0 = bx * 256;

  // inverse-swizzled global source for linear global_load_lds dest
  const int s_log = (tid * 16) ^ (((tid >> 3) & 7) << 4);
  const int rsw = s_log >> 7;
  const int csw = (s_log & 127) >> 1;
  const unsigned short* aSrc = A + (size_t)(m0 + rsw) * K + csw;
  const unsigned short* bSrc = B + (size_t)(n0 + rsw) * K + csw;

  char* const ldsAw = smem + wid * 1024;           // wave-uniform stage bases
  char* const ldsBw = smem + 65536 + wid * 1024;

  // 4 lane-base pointers: all fragment reads are base + compile-time offset
  const int s7 = (fr & 7) << 4;
  const char* const aB0 = smem + (wr128 + fr) * 128 + (q16 ^ s7);
  const char* const aB1 = smem + (wr128 + fr) * 128 + ((64 + q16) ^ s7);
  const char* const bB0 = smem + 65536 + (wc64 + fr) * 128 + (q16 ^ s7);
  const char* const bB1 = smem + 65536 + (wc64 + fr) * 128 + ((64 + q16) ^ s7);

  f32x4 acc[8][4] = {};
  short8_t af[4][2], bfr[4][2];

  // ---- prologue: ktile0 -> slot0 (8 units), ktile1 -> slot1 (6 units) ----
  STAGE_A(0,0,0); STAGE_A(0,1,0); STAGE_A(0,2,0); STAGE_A(0,3,0);
  STAGE_B(0,0,0); STAGE_B(0,1,0); STAGE_B(0,2,0); STAGE_B(0,3,0);
  STAGE_A(1,0,1); STAGE_A(1,1,1); STAGE_A(1,2,1); STAGE_A(1,3,1);
  STAGE_B(1,0,1); STAGE_B(1,1,1);
  asm volatile("s_waitcnt vmcnt(6)" ::: "memory");   // slot0 landed
  __builtin_amdgcn_s_barrier();
  asm volatile("" ::: "memory");

  const int NT = K >> 7;   // 2 K-tiles (2*64) per iteration
  for (int t = 0; t < NT - 1; ++t) {
    const int k1 = 2*t + 1, k2 = 2*t + 2, k3 = 2*t + 3;
    // P1: 12 ds_reads; stage slot1 B-tail (lands by P4 vmcnt)
    READ_A(0, 0) READ_B(0, 0)
    STAGE_B(1,2,k1); STAGE_B(1,3,k1);
    PH_MID; MFMA_Q(0,0) PH_END;
    // P2: stage slot0 A units 0,2 (freed by P1 reads)
    READ_B(0, 1)
    STAGE_A(0,0,k2); STAGE_A(0,2,k2);
    PH_MID; MFMA_Q(0,1) PH_END;
    // P3: stage slot0 B units 0,1
    READ_A(0, 1)
    STAGE_B(0,0,k2); STAGE_B(0,1,k2);
    PH_MID; MFMA_Q(1,0) PH_END;
    // P4: stage slot0 A units 1,3; counted vmcnt -> slot1 landed
    STAGE_A(0,1,k2); STAGE_A(0,3,k2);
    PH_MID; MFMA_Q(1,1) PH_END_V(6);
    // P5: 12 ds_reads on slot1; stage slot0 B units 2,3
    READ_A(1, 0) READ_B(1, 0)
    STAGE_B(0,2,k2); STAGE_B(0,3,k2);
    PH_MID; MFMA_Q(0,0) PH_END;
    // P6: stage slot1 A units 0,2
    READ_B(1, 1)
    STAGE_A(1,0,k3); STAGE_A(1,2,k3);
    PH_MID; MFMA_Q(0,1) PH_END;
    // P7: stage slot1 B units 0,1
    READ_A(1, 1)
    STAGE_B(1,0,k3); STAGE_B(1,1,k3);
    PH_MID; MFMA_Q(1,0) PH_END;
    // P8: stage slot1 A units 1,3; counted vmcnt -> slot0 landed
    STAGE_A(1,1,k3); STAGE_A(1,3,k3);
    PH_MID; MFMA_Q(1,1) PH_END_V(6);
  }
  // ---- final iteration: only the slot1 B-tail stage remains ----
  {
    const int k1 = 2*NT - 1;
    READ_A(0, 0) READ_B(0, 0)
    STAGE_B(1,2,k1); STAGE_B(1,3,k1);
    PH_MID; MFMA_Q(0,0) PH_END;
    READ_B(0, 1)
    PH_MID; MFMA_Q(0,1) PH_END;
    READ_A(0, 1)
    PH_MID; MFMA_Q(1,0) PH_END;
    PH_MID; MFMA_Q(1,1) PH_END_V(0);
    READ_A(1, 0) READ_B(1, 0)
    PH_MID; MFMA_Q(0,0) PH_END;
    READ_B(1, 1)
    PH_MID; MFMA_Q(0,1) PH_END;
    READ_A(1, 1)
    PH_MID; MFMA_Q(1,0) PH_END;
    PH_MID; MFMA_Q(1,1)
    __builtin_amdgcn_s_setprio(0);
  }

  // ---- epilogue: LDS-transpose -> fully-contiguous 1KB nt stores ----
  __syncthreads();   // all waves' K-loop LDS reads done before overwrite
  float* const buf0 = (float*)smem;
  float* const buf1 = (float*)smem + 64 * 260;
  const int cr = (lane >> 4) * 4;
  float bv[4];
#pragma unroll
  for (int ni = 0; ni < 4; ++ni) bv[ni] = bias[n0 + wc64 + ni * 16 + fr];

#pragma unroll
  for (int half = 0; half < 2; ++half) {
    float* const wbuf = (wr == 0) ? buf0 : buf1;
#pragma unroll
    for (int mi4 = 0; mi4 < 4; ++mi4) {
      const int mi = half * 4 + mi4;
#pragma unroll
      for (int j = 0; j < 4; ++j) {
        const int lr = mi4 * 16 + cr + j;   // local row 0..63
#pragma unroll
        for (int ni = 0; ni < 4; ++ni)
          wbuf[lr * 260 + wc64 + ni * 16 + fr] = acc[mi][ni][j] + bv[ni];
      }
    }
    __syncthreads();
#pragma unroll
    for (int i = 0; i < 16; ++i) {
      const int idx = wid * 16 + i;   // 0..127, wave-uniform buffer choice
      const float* src = (idx < 64 ? buf0 + idx * 260 : buf1 + (idx - 64) * 260) + lane * 4;
      const int grow = m0 + (idx < 64 ? half * 64 + idx : 128 + half * 64 + (idx - 64));
      const f32x4 vv = *reinterpret_cast<const f32x4*>(src);
      __builtin_nontemporal_store(
          vv, reinterpret_cast<f32x4*>(C + (size_t)grow * N + n0) + lane);
    }
    __syncthreads();
  }
}

extern "C" void kernel_launch(void* const* d_in, const int* in_sizes, int n_in,
                              void* d_out, int out_size, void* d_ws, size_t ws_size,
                              hipStream_t stream) {
  const float* x    = (const float*)d_in[0];
  const float* w    = (const float*)d_in[1];
  const float* bias = (const float*)d_in[2];
  const float* lnw  = (const float*)d_in[3];
  const float* lnb  = (const float*)d_in[4];
  float* out = (float*)d_out;

  const int DIN  = 4096;
  const int M    = in_sizes[0] / DIN;      // 8192
  const int DOUT = in_sizes[2];            // 12288

  unsigned short* normA = (unsigned short*)d_ws;                 // M x DIN bf16
  unsigned short* wB    = normA + (size_t)M * DIN;               // DOUT x DIN bf16

  ln_bf16_kernel<<<M, 256, 0, stream>>>(x, lnw, lnb, normA);
  f32_to_bf16_kernel<<<((size_t)DOUT * DIN) / (256 * 8), 256, 0, stream>>>(w, wB);

  const int nwg = (M / 256) * (DOUT / 256);   // 1536
  const int smem_bytes = 2 * 64 * 260 * 4 > 131072 ? 2 * 64 * 260 * 4 : 131072; // 133120
  (void)hipFuncSetAttribute((const void*)gemm_8phase,
                            hipFuncAttributeMaxDynamicSharedMemorySize, 163840);
  gemm_8phase<<<nwg, 512, smem_bytes, stream>>>(normA, wB, bias, out,
                                                M, DOUT, DIN, M / 256, (DOUT / 256) / 8);
}